// Round 10
// baseline (179.518 us; speedup 1.0000x reference)
//
#include <hip/hip_runtime.h>
#include <hip/hip_fp16.h>

#define TT 256
#define DD 128
#define NEG -30000.0f

typedef __attribute__((ext_vector_type(4))) float f32x4;
typedef __attribute__((ext_vector_type(8))) _Float16 f16x8;
typedef unsigned int u32;
typedef __attribute__((ext_vector_type(4))) u32 u32x4;
typedef unsigned short u16;

__device__ __forceinline__ u16 tof16(float v) {
  return __builtin_bit_cast(u16, (_Float16)v);
}
__device__ __forceinline__ u32 pkf16(float lo, float hi) {
  return (u32)tof16(lo) | ((u32)tof16(hi) << 16);
}
__device__ __forceinline__ f32x4 mfma16(f16x8 a, f16x8 b, f32x4 c) {
  return __builtin_amdgcn_mfma_f32_16x16x32_f16(a, b, c, 0, 0, 0);
}

// D-layout -> operand-frag repack (verified rounds 2-9). src[2P] D-tiles
// (rows t*16+g*4+j, col l15) -> dst[P] frags: lane(l15,g) holds packed f16 of
// M[col=l15][row=p*32+g*8+0..7].
template<int P>
__device__ __forceinline__ void convN(const f32x4* src, u32x4* dst, int l15, int g) {
  #pragma unroll
  for (int p = 0; p < P; ++p) {
    u32 p00 = pkf16(src[2*p][0], src[2*p][1]);
    u32 p01 = pkf16(src[2*p][2], src[2*p][3]);
    u32 p10 = pkf16(src[2*p+1][0], src[2*p+1][1]);
    u32 p11 = pkf16(src[2*p+1][2], src[2*p+1][3]);
    u32x4 w;
    #pragma unroll
    for (int wd = 0; wd < 4; ++wd) {
      int srcl = l15 + 16*((2*g + (wd >> 1)) & 3);
      u32 lo = (u32)__shfl((int)((wd & 1) ? p01 : p00), srcl, 64);
      u32 hi = (u32)__shfl((int)((wd & 1) ? p11 : p10), srcl, 64);
      w[wd] = (g >> 1) ? hi : lo;
    }
    dst[p] = w;
  }
}

// ---------------- precompute: MT[d'][d] = sum_e Wq[e][d]Wk[e][d']; WvB=f16(Wv);
// m0[d] = sum_e bq[e]Wk[e][d]   (verified round 2)
__global__ void precompute_k(const float* __restrict__ Wk, const float* __restrict__ Wq,
                             const float* __restrict__ bq, const float* __restrict__ Wv,
                             u16* __restrict__ MT, u16* __restrict__ WvB, float* __restrict__ m0) {
  int dp = blockIdx.x;
  int d  = threadIdx.x;
  float acc = 0.f;
  for (int e = 0; e < DD; ++e) acc = fmaf(Wq[e*DD + d], Wk[e*DD + dp], acc);
  MT[dp*DD + d] = tof16(acc);
  WvB[dp*DD + d] = tof16(Wv[dp*DD + d]);
  if (dp == 0) {
    float a0 = 0.f;
    for (int e = 0; e < DD; ++e) a0 = fmaf(bq[e], Wk[e*DD + d], a0);
    m0[d] = a0;
  }
}

// ---------------- per-q-tile pipeline (r9's verified 64-VGPR body):
// phaseA (A'-strip -> bAw), online-softmax chunk loop, epilogue store.
__device__ __forceinline__ void run_tile(int qt, const char* __restrict__ xhb,
                                         const char* __restrict__ vtb,
                                         const u16* __restrict__ MTg,
                                         const float* __restrict__ m0g,
                                         const float* __restrict__ bvg,
                                         float* __restrict__ outb,
                                         const int (&xoff)[4], int voff,
                                         int l15, int g) {
  // Phase A: A'[q][d'] strip -> B-frags bAw (verified)
  u32x4 bAw[4];
  {
    f16x8 bXq[4];
    #pragma unroll
    for (int kc = 0; kc < 4; ++kc)
      bXq[kc] = *(const f16x8*)(xhb + qt*4096 + xoff[kc]);
    f32x4 Aacc[8];
    #pragma unroll
    for (int dt = 0; dt < 8; ++dt) {
      f32x4 acc = {0.f, 0.f, 0.f, 0.f};
      #pragma unroll
      for (int kc = 0; kc < 4; ++kc) {
        f16x8 aM = *(const f16x8*)(MTg + (dt*16 + l15)*DD + kc*32 + g*8);
        acc = mfma16(aM, bXq[kc], acc);
      }
      f32x4 m0v = *(const f32x4*)(m0g + dt*16 + g*4);
      #pragma unroll
      for (int j = 0; j < 4; ++j) acc[j] += m0v[j];
      Aacc[dt] = acc;
    }
    convN<4>(Aacc, bAw, l15, g);
  }

  // Online chunk loop
  const int nch = (qt + 2) >> 1;
  f32x4 oacc[8];
  #pragma unroll
  for (int et = 0; et < 8; ++et) { f32x4 z = {0.f,0.f,0.f,0.f}; oacc[et] = z; }
  float m = NEG, sum = 0.f;

  #pragma unroll 1
  for (int c = 0; c < nch; ++c) {
    const int kt0 = 2*c, kt1 = 2*c + 1;
    f32x4 s0 = {0.f, 0.f, 0.f, 0.f};
    f32x4 s1 = {NEG, NEG, NEG, NEG};
    #pragma unroll
    for (int kc = 0; kc < 4; ++kc) {
      f16x8 aX = *(const f16x8*)(xhb + kt0*4096 + xoff[kc]);
      s0 = mfma16(aX, __builtin_bit_cast(f16x8, bAw[kc]), s0);
    }
    if (kt0 == qt) {
      #pragma unroll
      for (int j = 0; j < 4; ++j)
        if (g*4 + j > l15) s0[j] = NEG;
    }
    if (kt1 <= qt) {
      f32x4 acc = {0.f, 0.f, 0.f, 0.f};
      #pragma unroll
      for (int kc = 0; kc < 4; ++kc) {
        f16x8 aX = *(const f16x8*)(xhb + kt1*4096 + xoff[kc]);
        acc = mfma16(aX, __builtin_bit_cast(f16x8, bAw[kc]), acc);
      }
      if (kt1 == qt) {
        #pragma unroll
        for (int j = 0; j < 4; ++j)
          if (g*4 + j > l15) acc[j] = NEG;
      }
      s1 = acc;
    }
    float pmax = NEG;
    #pragma unroll
    for (int j = 0; j < 4; ++j) pmax = fmaxf(pmax, fmaxf(s0[j], s1[j]));
    pmax = fmaxf(pmax, __shfl_xor(pmax, 16));
    pmax = fmaxf(pmax, __shfl_xor(pmax, 32));
    if (!__all(pmax <= m + 8.f)) {
      float mn = fmaxf(m, pmax);
      float f  = __expf(m - mn);        // 0 on first chunk (m=NEG)
      sum *= f;
      #pragma unroll
      for (int et = 0; et < 8; ++et) {
        #pragma unroll
        for (int j = 0; j < 4; ++j) oacc[et][j] *= f;
      }
      m = mn;
    }
    #pragma unroll
    for (int j = 0; j < 4; ++j) {
      float p0 = __expf(s0[j] - m); s0[j] = p0; sum += p0;
      float p1 = __expf(s1[j] - m); s1[j] = p1; sum += p1;   // 0 if kt1 invalid
    }
    u32 p00 = pkf16(s0[0], s0[1]);
    u32 p01 = pkf16(s0[2], s0[3]);
    u32 p10 = pkf16(s1[0], s1[1]);
    u32 p11 = pkf16(s1[2], s1[3]);
    u32x4 pw;
    #pragma unroll
    for (int wd = 0; wd < 4; ++wd) {
      int srcl = l15 + 16*((2*g + (wd >> 1)) & 3);
      u32 lo = (u32)__shfl((int)((wd & 1) ? p01 : p00), srcl, 64);
      u32 hi = (u32)__shfl((int)((wd & 1) ? p11 : p10), srcl, 64);
      pw[wd] = (g >> 1) ? hi : lo;
    }
    f16x8 pb = __builtin_bit_cast(f16x8, pw);
    #pragma unroll
    for (int et = 0; et < 8; ++et) {
      f16x8 aV = *(const f16x8*)(vtb + et*8192 + c*1024 + voff);
      oacc[et] = mfma16(aV, pb, oacc[et]);
    }
  }

  // Epilogue: normalize + bv; store (verified layout)
  sum += __shfl_xor(sum, 16);
  sum += __shfl_xor(sum, 32);
  const float inv = 1.f / sum;
  #pragma unroll
  for (int et = 0; et < 8; ++et) {
    f32x4 bvv = *(const f32x4*)(bvg + et*16 + g*4);
    f32x4 o;
    #pragma unroll
    for (int j = 0; j < 4; ++j) o[j] = oacc[et][j]*inv + bvv[j];
    *(f32x4*)(outb + (qt*16 + l15)*DD + et*16 + g*4) = o;
  }
}

// ---------------- fused head: 1 block = 1 batch, 16 waves, 128 KB LDS.
// Wave w processes q-tiles {15-w, w} SEQUENTIALLY: nch(15-w)+nch(w) = 9 chunks
// for every wave -> perfectly balanced causal work, one oacc state at a time.
__global__ __launch_bounds__(1024, 4)
void head_fused(const float* __restrict__ x, const u16* __restrict__ MTg,
                const u16* __restrict__ WvB, const float* __restrict__ m0g,
                const float* __restrict__ bvg, float* __restrict__ out) {
  extern __shared__ char lds[];
  char* xhb = lds;            // xh frags (64 KB, swizzled: l15s = l15 ^ (kc*4+g))
  char* vtb = lds + 65536;    // vt frags (64 KB, linear)

  const int tid  = threadIdx.x;
  const int w    = tid >> 6;
  const int lane = tid & 63;
  const int l15  = lane & 15;
  const int g    = lane >> 4;
  const int b    = blockIdx.x;
  const float* xb = x + (size_t)b * (TT*DD);

  int xoff[4];
  #pragma unroll
  for (int kc = 0; kc < 4; ++kc)
    xoff[kc] = kc*1024 + g*256 + (l15 ^ (kc*4 + g))*16;
  const int voff = g*256 + l15*16;

  // ---- Stage: x f32 -> f16 frags in LDS (coalesced global, 2-way-max LDS)
  #pragma unroll
  for (int i = 0; i < 4; ++i) {
    int slot = tid + i*1024;
    int row = slot >> 4, cg = slot & 15;
    const float* p = xb + row*DD + cg*8;
    f32x4 v0 = *(const f32x4*)p, v1 = *(const f32x4*)(p + 4);
    u32x4 pk;
    pk[0] = pkf16(v0[0], v0[1]); pk[1] = pkf16(v0[2], v0[3]);
    pk[2] = pkf16(v1[0], v1[1]); pk[3] = pkf16(v1[2], v1[3]);
    *(u32x4*)(xhb + (row >> 4)*4096 + (cg >> 2)*1024 + (cg & 3)*256
                  + ((row & 15) ^ cg)*16) = pk;
  }
  __syncthreads();

  // ---- VT: wave w builds vt chunk c=w&7 for et-half w>>3 (verified math)
  {
    const int c = w & 7, eh = w >> 3;
    f16x8 bX[2][4];
    #pragma unroll
    for (int t = 0; t < 2; ++t)
      #pragma unroll
      for (int kc = 0; kc < 4; ++kc)
        bX[t][kc] = *(const f16x8*)(xhb + (2*c + t)*4096 + xoff[kc]);
    #pragma unroll
    for (int e = 0; e < 4; ++e) {
      const int et = eh*4 + e;
      f16x8 bWv[4];
      #pragma unroll
      for (int kc = 0; kc < 4; ++kc)
        bWv[kc] = *(const f16x8*)(WvB + (et*16 + l15)*DD + kc*32 + g*8);
      f32x4 vacc[2];
      #pragma unroll
      for (int t = 0; t < 2; ++t) {
        f32x4 acc = {0.f, 0.f, 0.f, 0.f};
        #pragma unroll
        for (int kc = 0; kc < 4; ++kc) acc = mfma16(bX[t][kc], bWv[kc], acc);
        vacc[t] = acc;
      }
      u32x4 dv[1];
      convN<1>(vacc, dv, l15, g);
      *(u32x4*)(vtb + et*8192 + c*1024 + voff) = dv[0];
    }
  }
  __syncthreads();

  // ---- Two balanced q-tiles per wave, sequential (register state reused)
  float* outb = out + (size_t)b * (TT*DD);
  run_tile(15 - w, xhb, vtb, MTg, m0g, bvg, outb, xoff, voff, l15, g);
  run_tile(w,      xhb, vtb, MTg, m0g, bvg, outb, xoff, voff, l15, g);
}

// ================= launcher =================
extern "C" void kernel_launch(void* const* d_in, const int* in_sizes, int n_in,
                              void* d_out, int out_size, void* d_ws, size_t ws_size,
                              hipStream_t stream) {
  (void)in_sizes; (void)n_in; (void)out_size; (void)ws_size;
  const float* x  = (const float*)d_in[0];
  const float* Wk = (const float*)d_in[1];
  // d_in[2] = bk: only per-q-row constants in scores -> dropped by softmax
  const float* Wq = (const float*)d_in[3];
  const float* bq = (const float*)d_in[4];
  const float* Wv = (const float*)d_in[5];
  const float* bv = (const float*)d_in[6];

  char* ws = (char*)d_ws;
  u16*   MT  = (u16*)ws;               // 32 KB
  u16*   WvB = (u16*)(ws + 32768);     // 32 KB
  float* m0  = (float*)(ws + 65536);   // 512 B

  (void)hipFuncSetAttribute((const void*)head_fused,
                            hipFuncAttributeMaxDynamicSharedMemorySize, 131072);

  precompute_k<<<128, 128, 0, stream>>>(Wk, Wq, bq, Wv, MT, WvB, m0);
  head_fused<<<512, 1024, 131072, stream>>>(x, MT, WvB, m0, bv, (float*)d_out);
}

// Round 11
// 83.095 us; speedup vs baseline: 2.1604x; 2.1604x over previous
//
#include <hip/hip_runtime.h>
#include <hip/hip_fp16.h>

#define TT 256
#define DD 128
#define NEG -30000.0f

typedef __attribute__((ext_vector_type(4))) float f32x4;
typedef __attribute__((ext_vector_type(8))) _Float16 f16x8;
typedef unsigned int u32;
typedef __attribute__((ext_vector_type(4))) u32 u32x4;
typedef unsigned short u16;

__device__ __forceinline__ u16 tof16(float v) {
  return __builtin_bit_cast(u16, (_Float16)v);
}
__device__ __forceinline__ u32 pkf16(float lo, float hi) {
  return (u32)tof16(lo) | ((u32)tof16(hi) << 16);
}
__device__ __forceinline__ f32x4 mfma16(f16x8 a, f16x8 b, f32x4 c) {
  return __builtin_amdgcn_mfma_f32_16x16x32_f16(a, b, c, 0, 0, 0);
}

// D-layout -> operand-frag repack (verified rounds 2-10). src[2P] D-tiles
// (rows t*16+g*4+j, col l15) -> dst[P] frags: lane(l15,g) holds packed f16 of
// M[col=l15][row=p*32+g*8+0..7].
template<int P>
__device__ __forceinline__ void convN(const f32x4* src, u32x4* dst, int l15, int g) {
  #pragma unroll
  for (int p = 0; p < P; ++p) {
    u32 p00 = pkf16(src[2*p][0], src[2*p][1]);
    u32 p01 = pkf16(src[2*p][2], src[2*p][3]);
    u32 p10 = pkf16(src[2*p+1][0], src[2*p+1][1]);
    u32 p11 = pkf16(src[2*p+1][2], src[2*p+1][3]);
    u32x4 w;
    #pragma unroll
    for (int wd = 0; wd < 4; ++wd) {
      int srcl = l15 + 16*((2*g + (wd >> 1)) & 3);
      u32 lo = (u32)__shfl((int)((wd & 1) ? p01 : p00), srcl, 64);
      u32 hi = (u32)__shfl((int)((wd & 1) ? p11 : p10), srcl, 64);
      w[wd] = (g >> 1) ? hi : lo;
    }
    dst[p] = w;
  }
}

// ---------------- precompute: MT[d'][d] = sum_e Wq[e][d]Wk[e][d']; WvB=f16(Wv);
// m0[d] = sum_e bq[e]Wk[e][d]   (verified round 2)
__global__ void precompute_k(const float* __restrict__ Wk, const float* __restrict__ Wq,
                             const float* __restrict__ bq, const float* __restrict__ Wv,
                             u16* __restrict__ MT, u16* __restrict__ WvB, float* __restrict__ m0) {
  int dp = blockIdx.x;
  int d  = threadIdx.x;
  float acc = 0.f;
  for (int e = 0; e < DD; ++e) acc = fmaf(Wq[e*DD + d], Wk[e*DD + dp], acc);
  MT[dp*DD + d] = tof16(acc);
  WvB[dp*DD + d] = tof16(Wv[dp*DD + d]);
  if (dp == 0) {
    float a0 = 0.f;
    for (int e = 0; e < DD; ++e) a0 = fmaf(bq[e], Wk[e*DD + d], a0);
    m0[d] = a0;
  }
}

// ---------------- per-q-tile pipeline (r9's verified body):
// phaseA (A'-strip -> bAw), online-softmax chunk loop, epilogue store.
__device__ __forceinline__ void run_tile(int qt, const char* __restrict__ xhb,
                                         const char* __restrict__ vtb,
                                         const u16* __restrict__ MTg,
                                         const float* __restrict__ m0g,
                                         const float* __restrict__ bvg,
                                         float* __restrict__ outb,
                                         const int (&xoff)[4], int voff,
                                         int l15, int g) {
  // Phase A: A'[q][d'] strip -> B-frags bAw (verified)
  u32x4 bAw[4];
  {
    f16x8 bXq[4];
    #pragma unroll
    for (int kc = 0; kc < 4; ++kc)
      bXq[kc] = *(const f16x8*)(xhb + qt*4096 + xoff[kc]);
    f32x4 Aacc[8];
    #pragma unroll
    for (int dt = 0; dt < 8; ++dt) {
      f32x4 acc = {0.f, 0.f, 0.f, 0.f};
      #pragma unroll
      for (int kc = 0; kc < 4; ++kc) {
        f16x8 aM = *(const f16x8*)(MTg + (dt*16 + l15)*DD + kc*32 + g*8);
        acc = mfma16(aM, bXq[kc], acc);
      }
      f32x4 m0v = *(const f32x4*)(m0g + dt*16 + g*4);
      #pragma unroll
      for (int j = 0; j < 4; ++j) acc[j] += m0v[j];
      Aacc[dt] = acc;
    }
    convN<4>(Aacc, bAw, l15, g);
  }

  // Online chunk loop
  const int nch = (qt + 2) >> 1;
  f32x4 oacc[8];
  #pragma unroll
  for (int et = 0; et < 8; ++et) { f32x4 z = {0.f,0.f,0.f,0.f}; oacc[et] = z; }
  float m = NEG, sum = 0.f;

  #pragma unroll 1
  for (int c = 0; c < nch; ++c) {
    const int kt0 = 2*c, kt1 = 2*c + 1;
    f32x4 s0 = {0.f, 0.f, 0.f, 0.f};
    f32x4 s1 = {NEG, NEG, NEG, NEG};
    #pragma unroll
    for (int kc = 0; kc < 4; ++kc) {
      f16x8 aX = *(const f16x8*)(xhb + kt0*4096 + xoff[kc]);
      s0 = mfma16(aX, __builtin_bit_cast(f16x8, bAw[kc]), s0);
    }
    if (kt0 == qt) {
      #pragma unroll
      for (int j = 0; j < 4; ++j)
        if (g*4 + j > l15) s0[j] = NEG;
    }
    if (kt1 <= qt) {
      f32x4 acc = {0.f, 0.f, 0.f, 0.f};
      #pragma unroll
      for (int kc = 0; kc < 4; ++kc) {
        f16x8 aX = *(const f16x8*)(xhb + kt1*4096 + xoff[kc]);
        acc = mfma16(aX, __builtin_bit_cast(f16x8, bAw[kc]), acc);
      }
      if (kt1 == qt) {
        #pragma unroll
        for (int j = 0; j < 4; ++j)
          if (g*4 + j > l15) acc[j] = NEG;
      }
      s1 = acc;
    }
    float pmax = NEG;
    #pragma unroll
    for (int j = 0; j < 4; ++j) pmax = fmaxf(pmax, fmaxf(s0[j], s1[j]));
    pmax = fmaxf(pmax, __shfl_xor(pmax, 16));
    pmax = fmaxf(pmax, __shfl_xor(pmax, 32));
    if (!__all(pmax <= m + 8.f)) {
      float mn = fmaxf(m, pmax);
      float f  = __expf(m - mn);        // 0 on first chunk (m=NEG)
      sum *= f;
      #pragma unroll
      for (int et = 0; et < 8; ++et) {
        #pragma unroll
        for (int j = 0; j < 4; ++j) oacc[et][j] *= f;
      }
      m = mn;
    }
    #pragma unroll
    for (int j = 0; j < 4; ++j) {
      float p0 = __expf(s0[j] - m); s0[j] = p0; sum += p0;
      float p1 = __expf(s1[j] - m); s1[j] = p1; sum += p1;   // 0 if kt1 invalid
    }
    u32 p00 = pkf16(s0[0], s0[1]);
    u32 p01 = pkf16(s0[2], s0[3]);
    u32 p10 = pkf16(s1[0], s1[1]);
    u32 p11 = pkf16(s1[2], s1[3]);
    u32x4 pw;
    #pragma unroll
    for (int wd = 0; wd < 4; ++wd) {
      int srcl = l15 + 16*((2*g + (wd >> 1)) & 3);
      u32 lo = (u32)__shfl((int)((wd & 1) ? p01 : p00), srcl, 64);
      u32 hi = (u32)__shfl((int)((wd & 1) ? p11 : p10), srcl, 64);
      pw[wd] = (g >> 1) ? hi : lo;
    }
    f16x8 pb = __builtin_bit_cast(f16x8, pw);
    #pragma unroll
    for (int et = 0; et < 8; ++et) {
      f16x8 aV = *(const f16x8*)(vtb + et*8192 + c*1024 + voff);
      oacc[et] = mfma16(aV, pb, oacc[et]);
    }
  }

  // Epilogue: normalize + bv; store (verified layout)
  sum += __shfl_xor(sum, 16);
  sum += __shfl_xor(sum, 32);
  const float inv = 1.f / sum;
  #pragma unroll
  for (int et = 0; et < 8; ++et) {
    f32x4 bvv = *(const f32x4*)(bvg + et*16 + g*4);
    f32x4 o;
    #pragma unroll
    for (int j = 0; j < 4; ++j) o[j] = oacc[et][j]*inv + bvv[j];
    *(f32x4*)(outb + (qt*16 + l15)*DD + et*16 + g*4) = o;
  }
}

// ---------------- fused head: 1 block = 1 batch, 8 waves (512 thr), 128 KB LDS.
// launch_bounds(512,2) -> 256-VGPR budget: the two sequential tiles per wave
// can interleave in registers WITHOUT spilling (r10's failure mode at 128 cap).
// Wave w handles q-tiles {15-w, w}: nch sums to 9 chunks for every wave.
__global__ __launch_bounds__(512, 2)
void head_fused(const float* __restrict__ x, const u16* __restrict__ MTg,
                const u16* __restrict__ WvB, const float* __restrict__ m0g,
                const float* __restrict__ bvg, float* __restrict__ out) {
  extern __shared__ char lds[];
  char* xhb = lds;            // xh frags (64 KB, swizzled: l15s = l15 ^ (kc*4+g))
  char* vtb = lds + 65536;    // vt frags (64 KB, linear)

  const int tid  = threadIdx.x;
  const int w    = tid >> 6;
  const int lane = tid & 63;
  const int l15  = lane & 15;
  const int g    = lane >> 4;
  const int b    = blockIdx.x;
  const float* xb = x + (size_t)b * (TT*DD);

  int xoff[4];
  #pragma unroll
  for (int kc = 0; kc < 4; ++kc)
    xoff[kc] = kc*1024 + g*256 + (l15 ^ (kc*4 + g))*16;
  const int voff = g*256 + l15*16;

  // ---- Stage: x f32 -> f16 frags in LDS (coalesced global, 2-way-max LDS)
  #pragma unroll
  for (int i = 0; i < 8; ++i) {
    int slot = tid + i*512;
    int row = slot >> 4, cg = slot & 15;
    const float* p = xb + row*DD + cg*8;
    f32x4 v0 = *(const f32x4*)p, v1 = *(const f32x4*)(p + 4);
    u32x4 pk;
    pk[0] = pkf16(v0[0], v0[1]); pk[1] = pkf16(v0[2], v0[3]);
    pk[2] = pkf16(v1[0], v1[1]); pk[3] = pkf16(v1[2], v1[3]);
    *(u32x4*)(xhb + (row >> 4)*4096 + (cg >> 2)*1024 + (cg & 3)*256
                  + ((row & 15) ^ cg)*16) = pk;
  }
  __syncthreads();

  // ---- VT: wave w builds vt chunk c=w, all 8 et (verified r8/r9 math)
  {
    const int c = w;
    f16x8 bX[2][4];
    #pragma unroll
    for (int t = 0; t < 2; ++t)
      #pragma unroll
      for (int kc = 0; kc < 4; ++kc)
        bX[t][kc] = *(const f16x8*)(xhb + (2*c + t)*4096 + xoff[kc]);
    #pragma unroll
    for (int et = 0; et < 8; ++et) {
      f16x8 bWv[4];
      #pragma unroll
      for (int kc = 0; kc < 4; ++kc)
        bWv[kc] = *(const f16x8*)(WvB + (et*16 + l15)*DD + kc*32 + g*8);
      f32x4 vacc[2];
      #pragma unroll
      for (int t = 0; t < 2; ++t) {
        f32x4 acc = {0.f, 0.f, 0.f, 0.f};
        #pragma unroll
        for (int kc = 0; kc < 4; ++kc) acc = mfma16(bX[t][kc], bWv[kc], acc);
        vacc[t] = acc;
      }
      u32x4 dv[1];
      convN<1>(vacc, dv, l15, g);
      *(u32x4*)(vtb + et*8192 + c*1024 + voff) = dv[0];
    }
  }
  __syncthreads();

  // ---- Two balanced q-tiles per wave, sequential (9 chunks total per wave)
  float* outb = out + (size_t)b * (TT*DD);
  run_tile(15 - w, xhb, vtb, MTg, m0g, bvg, outb, xoff, voff, l15, g);
  run_tile(w,      xhb, vtb, MTg, m0g, bvg, outb, xoff, voff, l15, g);
}

// ================= launcher =================
extern "C" void kernel_launch(void* const* d_in, const int* in_sizes, int n_in,
                              void* d_out, int out_size, void* d_ws, size_t ws_size,
                              hipStream_t stream) {
  (void)in_sizes; (void)n_in; (void)out_size; (void)ws_size;
  const float* x  = (const float*)d_in[0];
  const float* Wk = (const float*)d_in[1];
  // d_in[2] = bk: only per-q-row constants in scores -> dropped by softmax
  const float* Wq = (const float*)d_in[3];
  const float* bq = (const float*)d_in[4];
  const float* Wv = (const float*)d_in[5];
  const float* bv = (const float*)d_in[6];

  char* ws = (char*)d_ws;
  u16*   MT  = (u16*)ws;               // 32 KB
  u16*   WvB = (u16*)(ws + 32768);     // 32 KB
  float* m0  = (float*)(ws + 65536);   // 512 B

  (void)hipFuncSetAttribute((const void*)head_fused,
                            hipFuncAttributeMaxDynamicSharedMemorySize, 131072);

  precompute_k<<<128, 128, 0, stream>>>(Wk, Wq, bq, Wv, MT, WvB, m0);
  head_fused<<<512, 512, 131072, stream>>>(x, MT, WvB, m0, bv, (float*)d_out);
}